// Round 13
// baseline (54.035 us; speedup 1.0000x reference)
//
#include <hip/hip_runtime.h>
#include <math.h>

typedef __bf16 bf16x8 __attribute__((ext_vector_type(8)));
typedef float f32x4 __attribute__((ext_vector_type(4)));
typedef unsigned short u16t;

namespace {
constexpr int B_ = 32, CIN = 16, CSP = 15, L_ = 16384;
constexpr int KS = 9, PAD = 4, OUTC = 64, NW = 63, CD = 136;
constexpr int PP = 256;        // positions per block
constexpr int NKS = 5;         // MFMA K-steps of 32
constexpr int XR = 268;        // staged rows
constexpr int RSTR = 24;       // Xt row stride in u16 (48 B)
constexpr int HTP = 68;        // hT row pitch in dwords (272 B)

constexpr int OFF_XT = 0;                                    // [268][24] u16 = 12864 B
constexpr int OFF_CSQ = OFF_XT + XR * RSTR * 2;              // 12864: [268] f32
constexpr int OFF_HT = ((OFF_CSQ + XR * 4 + 15) / 16) * 16;  // 13936: 4x[16][68] f32
constexpr int OFF_RED = OFF_HT + 4 * 16 * HTP * 4;           // 31344: [256] f32 (atomic)
constexpr int LDS_BYTES = OFF_RED + PP * 4;                  // 32368 B -> 5 blocks/CU
static_assert(LDS_BYTES <= 32 * 1024 + 512, "LDS overflow");

__device__ inline u16t f2bf(float v) {
  unsigned ui = __float_as_uint(v);
  return (u16t)((ui + 0x7fffu + ((ui >> 16) & 1u)) >> 16);
}
__device__ inline float bf2f(u16t u) { return __uint_as_float(((unsigned)u) << 16); }
}

__global__ __launch_bounds__(256, 5)
void lorentz_mfma(const float* __restrict__ x, const float* __restrict__ W,
                  const float* __restrict__ bias, float* __restrict__ out) {
  __shared__ __align__(16) char lds[LDS_BYTES];
  const int tid = threadIdx.x;
  const int b = blockIdx.y;
  const int p0 = blockIdx.x * PP;
  const int wv = tid >> 6;
  const int lane = tid & 63;
  const int q = lane >> 4, r = lane & 15;
  const int jtq = q >> 1, half = q & 1;
  const int row = 16 * wv + r;   // this lane's W row (output channel - 1)

  u16t* Xt = (u16t*)(lds + OFF_XT);
  float* csq = (float*)(lds + OFF_CSQ);
  float* ht = (float*)(lds + OFF_HT) + wv * 16 * HTP;  // wave-private transpose tile
  float* red = (float*)(lds + OFF_RED);                // [256] pos-wise h^2 accumulator

  // ---- inline W-fragment gather (replaces the prep_w kernel):
  // wfrag[ks] = bf16 x8 of W row `row`, k-slice [32ks+8q, +8) with
  // k = jt*16+cs mapping: jt = 2ks+jtq, cs = 8*half + e.  L2-resident (34 KB).
  uint4 wfrag[NKS];
  {
    const float* wr = W + (size_t)row * CD;
#pragma unroll
    for (int ks = 0; ks < NKS; ++ks) {
      const int jt = 2 * ks + jtq;
      union { u16t h[8]; uint4 u; } pk;
      if (row < NW && jt < KS) {
        const float* src = wr + 1 + jt * CSP + 8 * half;
#pragma unroll
        for (int e = 0; e < 8; ++e) {
          float v = (8 * half + e < CSP) ? src[e] : 0.f;  // cs==15 pad -> 0
          pk.h[e] = f2bf(v);
        }
      } else {
        pk.u = make_uint4(0, 0, 0, 0);
      }
      wfrag[ks] = pk.u;
    }
  }
  const float w0v = (row < NW) ? W[row * CD] : 0.f;
  const float bv = (row < NW) ? bias[row] : 0.f;

  // ---- P1: stage x position-major (cs 0..14 real, cs 15 zero) + zero red
  red[tid] = 0.f;
  for (int e4 = tid; e4 < 16 * (XR / 4); e4 += 256) {
    int cs = e4 / (XR / 4);
    int t4 = e4 - cs * (XR / 4);
    int t = 4 * t4;
    int g0 = p0 - PAD + t;
    float v0 = 0.f, v1 = 0.f, v2 = 0.f, v3 = 0.f;
    if (cs < CSP) {
      const float* src = x + ((size_t)b * CIN + cs + 1) * L_ + g0;
      if (g0 >= 0 && g0 + 3 < L_) {
        float4 v = *(const float4*)src;   // g0 % 4 == 0 -> 16B aligned
        v0 = v.x; v1 = v.y; v2 = v.z; v3 = v.w;
      } else {
        v0 = (g0 >= 0 && g0 < L_) ? src[0] : 0.f;
        v1 = (g0 + 1 >= 0 && g0 + 1 < L_) ? src[1] : 0.f;
        v2 = (g0 + 2 >= 0 && g0 + 2 < L_) ? src[2] : 0.f;
        v3 = (g0 + 3 >= 0 && g0 + 3 < L_) ? src[3] : 0.f;
      }
    }
    u16t* dst = Xt + t * RSTR + cs;
    dst[0] = f2bf(v0);
    dst[RSTR] = f2bf(v1);
    dst[2 * RSTR] = f2bf(v2);
    dst[3 * RSTR] = f2bf(v3);
  }
  __syncthreads();

  // ---- P2: per-window-column sum of squares
  for (int t = tid; t < XR; t += 256) {
    const uint4* rw4 = (const uint4*)(Xt + t * RSTR);
    uint4 a = rw4[0], c = rw4[1];
    unsigned wds[8] = {a.x, a.y, a.z, a.w, c.x, c.y, c.z, c.w};
    float s = 0.f;
#pragma unroll
    for (int i = 0; i < 8; ++i) {
      float lo = bf2f((u16t)(wds[i] & 0xffffu));
      float hi = bf2f((u16t)(wds[i] >> 16));
      s = fmaf(lo, lo, s);
      s = fmaf(hi, hi, s);
    }
    csq[t] = s;
  }
  __syncthreads();

  // ---- P3: 4 groups of 4 subtiles; wave-private LDS transpose; 256B-seg stores
  const int cl = lane >> 4;          // channel sub-index for the store pass
  const int pj = lane & 15;          // position quad within the 64-pos group
  for (int grp = 0; grp < 4; ++grp) {
    f32x4 hreg[4];
#pragma unroll
    for (int sl = 0; sl < 4; ++sl) {
      const int s = grp * 4 + sl;
      // A fragments: lane (q,r) holds patch[pos=s*16+r][k=32ks+8q .. +7]
      bf16x8 av[NKS];
#pragma unroll
      for (int ks = 0; ks < NKS; ++ks) {
        int xrow = s * 16 + r + 2 * ks + jtq;
        av[ks] = *(const bf16x8*)(lds + OFF_XT + xrow * (RSTR * 2) + half * 16);
      }
      f32x4 accA = {0.f, 0.f, 0.f, 0.f}, accB = {0.f, 0.f, 0.f, 0.f};
      {
        union { uint4 u; bf16x8 v; } w0, w1, w2, w3, w4;
        w0.u = wfrag[0]; w1.u = wfrag[1]; w2.u = wfrag[2];
        w3.u = wfrag[3]; w4.u = wfrag[4];
        accA = __builtin_amdgcn_mfma_f32_16x16x32_bf16(av[0], w0.v, accA, 0, 0, 0);
        accB = __builtin_amdgcn_mfma_f32_16x16x32_bf16(av[1], w1.v, accB, 0, 0, 0);
        accA = __builtin_amdgcn_mfma_f32_16x16x32_bf16(av[2], w2.v, accA, 0, 0, 0);
        accB = __builtin_amdgcn_mfma_f32_16x16x32_bf16(av[3], w3.v, accB, 0, 0, 0);
        accA = __builtin_amdgcn_mfma_f32_16x16x32_bf16(av[4], w4.v, accA, 0, 0, 0);
      }
      const f32x4 acc = accA + accB;

      // time channel from csq (running 9-window sums)
      const int base = s * 16 + q * 4;
      const f32x4* c4 = (const f32x4*)(csq + base);
      f32x4 ca = c4[0], cm = c4[1], cc = c4[2];
      float v[12] = {ca[0], ca[1], ca[2], ca[3], cm[0], cm[1], cm[2], cm[3],
                     cc[0], cc[1], cc[2], cc[3]};
      float ws0 = ((v[0] + v[1]) + (v[2] + v[3])) + ((v[4] + v[5]) + (v[6] + v[7])) + v[8];
      float ws1 = ws0 - v[0] + v[9];
      float ws2 = ws1 - v[1] + v[10];
      float ws3 = ws2 - v[2] + v[11];
      const float wsv[4] = {ws0, ws1, ws2, ws3};
      f32x4 hh;
#pragma unroll
      for (int g = 0; g < 4; ++g) {
        float tmg = sqrtf(1.f + wsv[g]);
        hh[g] = fmaxf(fmaf(w0v, tmg, acc[g]) + bv, 0.f);
      }
      hreg[sl] = hh;
    }

    // wave-private transpose: write [ch-local r][pos], read back [4j+cl][pj*4]
#pragma unroll
    for (int sl = 0; sl < 4; ++sl)
      *(f32x4*)(ht + r * HTP + sl * 16 + q * 4) = hreg[sl];

    f32x4 ps = {0.f, 0.f, 0.f, 0.f};
#pragma unroll
    for (int j = 0; j < 4; ++j) {
      const int rw = 4 * j + cl;               // tile-local channel row 0..15
      f32x4 hv = *(const f32x4*)(ht + rw * HTP + pj * 4);
      ps += hv * hv;
      const int oc = 16 * wv + rw;             // global W row
      if (oc < NW) {
        *(float4*)(out + ((size_t)b * OUTC + oc + 1) * L_ + p0 + grp * 64 + pj * 4) =
            make_float4(hv[0], hv[1], hv[2], hv[3]);
      }
    }
    // 16-channel sum per position, then one ds_add_f32 per lane into red
#pragma unroll
    for (int g = 0; g < 4; ++g) {
      ps[g] += __shfl_xor(ps[g], 16, 64);
      ps[g] += __shfl_xor(ps[g], 32, 64);
    }
    float pval = (cl == 0) ? ps[0] : (cl == 1) ? ps[1] : (cl == 2) ? ps[2] : ps[3];
    atomicAdd(&red[grp * 64 + pj * 4 + cl], pval);  // distinct addrs, conflict-free
  }
  __syncthreads();

  // ---- P4: t_out (channel 0) from red, contiguous 1KB store
  if (wv == 0) {
    const f32x4 s4 = *(const f32x4*)(red + 4 * lane);
    float4 t;
    t.x = sqrtf(1.f + s4[0]);
    t.y = sqrtf(1.f + s4[1]);
    t.z = sqrtf(1.f + s4[2]);
    t.w = sqrtf(1.f + s4[3]);
    *(float4*)(out + (size_t)b * OUTC * L_ + p0 + 4 * lane) = t;
  }
}

extern "C" void kernel_launch(void* const* d_in, const int* in_sizes, int n_in,
                              void* d_out, int out_size, void* d_ws, size_t ws_size,
                              hipStream_t stream) {
  const float* x = (const float*)d_in[0];
  const float* W = (const float*)d_in[1];
  const float* bias = (const float*)d_in[2];
  float* out = (float*)d_out;
  hipLaunchKernelGGL(lorentz_mfma, dim3(L_ / PP, B_), dim3(256), 0, stream,
                     x, W, bias, out);
}

// Round 14
// 48.109 us; speedup vs baseline: 1.1232x; 1.1232x over previous
//
#include <hip/hip_runtime.h>
#include <math.h>

typedef __bf16 bf16x8 __attribute__((ext_vector_type(8)));
typedef float f32x4 __attribute__((ext_vector_type(4)));
typedef unsigned short u16t;

namespace {
constexpr int B_ = 32, CIN = 16, CSP = 15, L_ = 16384;
constexpr int KS = 9, PAD = 4, OUTC = 64, NW = 63, CD = 136;
constexpr int PP = 256;        // positions per block
constexpr int KT = 160;        // padded K: 10 taps * 16 channel slots
constexpr int NKS = 5;         // MFMA K-steps of 32
constexpr int XR = 268;        // staged rows
constexpr int RSTR = 24;       // Xt row stride in u16 (48 B)
constexpr int HTP = 68;        // hT row pitch in dwords (272 B, bank-uniform)

constexpr int OFF_XT = 0;                                     // [268][24] u16 = 12864 B
constexpr int OFF_CSQ = OFF_XT + XR * RSTR * 2;               // 12864: [268] f32
constexpr int OFF_HT = ((OFF_CSQ + XR * 4 + 15) / 16) * 16;   // 13936: 4x[16][68] f32
constexpr int OFF_RED = OFF_HT + 4 * 16 * HTP * 4;            // 31344: [4][256] f32
constexpr int LDS_BYTES = OFF_RED + 4 * PP * 4;               // 35440 B -> 4 blocks/CU
static_assert(LDS_BYTES <= 64 * 1024, "LDS overflow");

__device__ inline u16t f2bf(float v) {
  unsigned ui = __float_as_uint(v);
  return (u16t)((ui + 0x7fffu + ((ui >> 16) & 1u)) >> 16);
}
__device__ inline float bf2f(u16t u) { return __uint_as_float(((unsigned)u) << 16); }
}

// Prepack W (63x136 fp32) -> wbf[64][160] bf16, k = jt*16 + cs; pads zeroed.
__global__ void prep_w(const float* __restrict__ W, u16t* __restrict__ wbf) {
  int i = blockIdx.x * 256 + threadIdx.x;
  if (i >= OUTC * KT) return;
  int o = i / KT, kk = i - o * KT;
  int jt = kk >> 4, cs = kk & 15;
  float v = 0.f;
  if (o < NW && jt < KS && cs < CSP) v = W[o * CD + 1 + jt * CSP + cs];
  wbf[i] = f2bf(v);
}

__global__ __launch_bounds__(256, 4)
void lorentz_mfma(const float* __restrict__ x, const float* __restrict__ W,
                  const float* __restrict__ bias, const u16t* __restrict__ wbf,
                  float* __restrict__ out) {
  __shared__ __align__(16) char lds[LDS_BYTES];
  const int tid = threadIdx.x;

  // XCD-aware bijective swizzle: nwg = 2048 = 8*256. XCD k receives flat ids
  // == k (mod 8); remap so each XCD owns 4 COMPLETE batches -> its L2 collects
  // contiguous output spans (write locality) instead of interleaved 1KB shards.
  const int flat = blockIdx.y * gridDim.x + blockIdx.x;   // 0..2047
  const int swz = (flat & 7) * 256 + (flat >> 3);
  const int b = swz >> 6;          // batch 0..31
  const int p0 = (swz & 63) * PP;  // position tile

  const int wv = tid >> 6;
  const int lane = tid & 63;
  const int q = lane >> 4, r = lane & 15;
  const int jtq = q >> 1, half = q & 1;
  const int row = 16 * wv + r;   // this lane's W row (output channel - 1)

  u16t* Xt = (u16t*)(lds + OFF_XT);
  float* csq = (float*)(lds + OFF_CSQ);
  float* ht = (float*)(lds + OFF_HT) + wv * 16 * HTP;  // wave-private transpose tile
  float* red = (float*)(lds + OFF_RED);

  // W fragments: 5 uint4 = 20 VGPR, register-resident.
  uint4 wfrag[NKS];
#pragma unroll
  for (int ks = 0; ks < NKS; ++ks)
    wfrag[ks] = *(const uint4*)(wbf + row * KT + ks * 32 + q * 8);
  const float w0v = (row < NW) ? W[row * CD] : 0.f;
  const float bv = (row < NW) ? bias[row] : 0.f;

  // ---- P1: stage x (channels 1..15) position-major, float4-vectorized
  for (int t = tid; t < XR; t += 256) Xt[t * RSTR + 15] = 0;  // dummy ch, NaN-safe
  for (int e4 = tid; e4 < CSP * (XR / 4); e4 += 256) {
    int cs = e4 / (XR / 4);
    int t4 = e4 - cs * (XR / 4);
    int t = 4 * t4;
    int g0 = p0 - PAD + t;
    const float* src = x + ((size_t)b * CIN + cs + 1) * L_ + g0;
    float v0, v1, v2, v3;
    if (g0 >= 0 && g0 + 3 < L_) {
      float4 v = *(const float4*)src;
      v0 = v.x; v1 = v.y; v2 = v.z; v3 = v.w;
    } else {
      v0 = (g0 >= 0 && g0 < L_) ? src[0] : 0.f;
      v1 = (g0 + 1 >= 0 && g0 + 1 < L_) ? src[1] : 0.f;
      v2 = (g0 + 2 >= 0 && g0 + 2 < L_) ? src[2] : 0.f;
      v3 = (g0 + 3 >= 0 && g0 + 3 < L_) ? src[3] : 0.f;
    }
    u16t* dst = Xt + t * RSTR + cs;
    dst[0] = f2bf(v0);
    dst[RSTR] = f2bf(v1);
    dst[2 * RSTR] = f2bf(v2);
    dst[3 * RSTR] = f2bf(v3);
  }
  __syncthreads();

  // ---- P2: per-window-column sum of squares
  for (int t = tid; t < XR; t += 256) {
    const uint4* rw4 = (const uint4*)(Xt + t * RSTR);
    uint4 a = rw4[0], c = rw4[1];
    unsigned wds[8] = {a.x, a.y, a.z, a.w, c.x, c.y, c.z, c.w};
    float s = 0.f;
#pragma unroll
    for (int i = 0; i < 8; ++i) {
      float lo = bf2f((u16t)(wds[i] & 0xffffu));
      float hi = bf2f((u16t)(wds[i] >> 16));
      s = fmaf(lo, lo, s);
      s = fmaf(hi, hi, s);
    }
    csq[t] = s;
  }
  __syncthreads();

  // ---- P3: 4 groups of 4 subtiles; wave-private LDS transpose; 256B-seg stores
  const int cl = lane >> 4;          // channel sub-index for the store pass
  const int pj = lane & 15;          // position quad within the 64-pos group
  for (int grp = 0; grp < 4; ++grp) {
    f32x4 hreg[4];
#pragma unroll
    for (int sl = 0; sl < 4; ++sl) {
      const int s = grp * 4 + sl;
      // A fragments: lane (q,r) holds patch[pos=s*16+r][k=32ks+8q .. +7]
      bf16x8 av[NKS];
#pragma unroll
      for (int ks = 0; ks < NKS; ++ks) {
        int xrow = s * 16 + r + 2 * ks + jtq;
        av[ks] = *(const bf16x8*)(lds + OFF_XT + xrow * (RSTR * 2) + half * 16);
      }
      f32x4 accA = {0.f, 0.f, 0.f, 0.f}, accB = {0.f, 0.f, 0.f, 0.f};
      {
        union { uint4 u; bf16x8 v; } w0, w1, w2, w3, w4;
        w0.u = wfrag[0]; w1.u = wfrag[1]; w2.u = wfrag[2];
        w3.u = wfrag[3]; w4.u = wfrag[4];
        accA = __builtin_amdgcn_mfma_f32_16x16x32_bf16(av[0], w0.v, accA, 0, 0, 0);
        accB = __builtin_amdgcn_mfma_f32_16x16x32_bf16(av[1], w1.v, accB, 0, 0, 0);
        accA = __builtin_amdgcn_mfma_f32_16x16x32_bf16(av[2], w2.v, accA, 0, 0, 0);
        accB = __builtin_amdgcn_mfma_f32_16x16x32_bf16(av[3], w3.v, accB, 0, 0, 0);
        accA = __builtin_amdgcn_mfma_f32_16x16x32_bf16(av[4], w4.v, accA, 0, 0, 0);
      }
      const f32x4 acc = accA + accB;

      // time channel from csq (running 9-window sums)
      const int base = s * 16 + q * 4;
      const f32x4* c4 = (const f32x4*)(csq + base);
      f32x4 ca = c4[0], cm = c4[1], cc = c4[2];
      float v[12] = {ca[0], ca[1], ca[2], ca[3], cm[0], cm[1], cm[2], cm[3],
                     cc[0], cc[1], cc[2], cc[3]};
      float ws0 = ((v[0] + v[1]) + (v[2] + v[3])) + ((v[4] + v[5]) + (v[6] + v[7])) + v[8];
      float ws1 = ws0 - v[0] + v[9];
      float ws2 = ws1 - v[1] + v[10];
      float ws3 = ws2 - v[2] + v[11];
      const float wsv[4] = {ws0, ws1, ws2, ws3};
      f32x4 hh;
#pragma unroll
      for (int g = 0; g < 4; ++g) {
        float tmg = sqrtf(1.f + wsv[g]);
        hh[g] = fmaxf(fmaf(w0v, tmg, acc[g]) + bv, 0.f);
      }
      hreg[sl] = hh;
    }

    // wave-private transpose: write [ch-local r][pos], read back [4j+cl][pj*4]
#pragma unroll
    for (int sl = 0; sl < 4; ++sl)
      *(f32x4*)(ht + r * HTP + sl * 16 + q * 4) = hreg[sl];

    f32x4 ps = {0.f, 0.f, 0.f, 0.f};
#pragma unroll
    for (int j = 0; j < 4; ++j) {
      const int rw = 4 * j + cl;               // tile-local channel row 0..15
      f32x4 hv = *(const f32x4*)(ht + rw * HTP + pj * 4);
      ps += hv * hv;
      const int oc = 16 * wv + rw;             // global W row
      if (oc < NW) {
        *(float4*)(out + ((size_t)b * OUTC + oc + 1) * L_ + p0 + grp * 64 + pj * 4) =
            make_float4(hv[0], hv[1], hv[2], hv[3]);
      }
    }
    // reduce ps over the 4 cl-groups -> 16-channel partial for this wave
#pragma unroll
    for (int g = 0; g < 4; ++g) {
      ps[g] += __shfl_xor(ps[g], 16, 64);
      ps[g] += __shfl_xor(ps[g], 32, 64);
    }
    if (lane < 16)
      *(f32x4*)(red + wv * PP + grp * 64 + lane * 4) = ps;
  }
  __syncthreads();

  // ---- P4: cross-wave combine -> t_out (channel 0), contiguous 1KB store
  if (wv == 0) {
    const f32x4* r4 = (const f32x4*)red;
    f32x4 s0 = r4[lane], s1 = r4[64 + lane], s2 = r4[128 + lane], s3 = r4[192 + lane];
    float4 t;
    t.x = sqrtf(1.f + s0[0] + s1[0] + s2[0] + s3[0]);
    t.y = sqrtf(1.f + s0[1] + s1[1] + s2[1] + s3[1]);
    t.z = sqrtf(1.f + s0[2] + s1[2] + s2[2] + s3[2]);
    t.w = sqrtf(1.f + s0[3] + s1[3] + s2[3] + s3[3]);
    *(float4*)(out + (size_t)b * OUTC * L_ + p0 + 4 * lane) = t;
  }
}

extern "C" void kernel_launch(void* const* d_in, const int* in_sizes, int n_in,
                              void* d_out, int out_size, void* d_ws, size_t ws_size,
                              hipStream_t stream) {
  const float* x = (const float*)d_in[0];
  const float* W = (const float*)d_in[1];
  const float* bias = (const float*)d_in[2];
  float* out = (float*)d_out;
  u16t* wbf = (u16t*)d_ws;  // 64*160*2 = 20480 B

  hipLaunchKernelGGL(prep_w, dim3((OUTC * KT + 255) / 256), dim3(256), 0, stream, W, wbf);
  hipLaunchKernelGGL(lorentz_mfma, dim3(L_ / PP, B_), dim3(256), 0, stream,
                     x, W, bias, wbf, out);
}

// Round 16
// 47.207 us; speedup vs baseline: 1.1446x; 1.0191x over previous
//
#include <hip/hip_runtime.h>
#include <math.h>

typedef __bf16 bf16x8 __attribute__((ext_vector_type(8)));
typedef float f32x4 __attribute__((ext_vector_type(4)));
typedef unsigned short u16t;

namespace {
constexpr int B_ = 32, CIN = 16, CSP = 15, L_ = 16384;
constexpr int KS = 9, PAD = 4, OUTC = 64, NW = 63, CD = 136;
constexpr int PP = 256;        // positions per block
constexpr int KT = 160;        // padded K: 10 taps * 16 channel slots
constexpr int NKS = 5;         // MFMA K-steps of 32
constexpr int XR = 268;        // staged rows
constexpr int RSTR = 24;       // Xt row stride in u16 (48 B)
constexpr int HTP = 68;        // hT row pitch in dwords (272 B, bank-uniform)

constexpr int OFF_XT = 0;                                     // [268][24] u16 = 12864 B
constexpr int OFF_CSQ = OFF_XT + XR * RSTR * 2;               // 12864: [268] f32
constexpr int OFF_HT = ((OFF_CSQ + XR * 4 + 15) / 16) * 16;   // 13936: 4x[16][68] f32
constexpr int OFF_RED = OFF_HT + 4 * 16 * HTP * 4;            // 31344: [4][256] f32
constexpr int LDS_BYTES = OFF_RED + 4 * PP * 4;               // 35440 B -> 4 blocks/CU
static_assert(LDS_BYTES <= 64 * 1024, "LDS overflow");

__device__ inline u16t f2bf(float v) {
  unsigned ui = __float_as_uint(v);
  return (u16t)((ui + 0x7fffu + ((ui >> 16) & 1u)) >> 16);
}
__device__ inline float bf2f(u16t u) { return __uint_as_float(((unsigned)u) << 16); }

__device__ inline void nt_store4(float* p, float a, float b, float c, float d) {
  f32x4 v = {a, b, c, d};                       // native ext-vector: builtin-legal
  __builtin_nontemporal_store(v, (f32x4*)p);    // global_store_dwordx4 ... nt
}
}

// Prepack W (63x136 fp32) -> wbf[64][160] bf16, k = jt*16 + cs; pads zeroed.
__global__ void prep_w(const float* __restrict__ W, u16t* __restrict__ wbf) {
  int i = blockIdx.x * 256 + threadIdx.x;
  if (i >= OUTC * KT) return;
  int o = i / KT, kk = i - o * KT;
  int jt = kk >> 4, cs = kk & 15;
  float v = 0.f;
  if (o < NW && jt < KS && cs < CSP) v = W[o * CD + 1 + jt * CSP + cs];
  wbf[i] = f2bf(v);
}

__global__ __launch_bounds__(256, 4)
void lorentz_mfma(const float* __restrict__ x, const float* __restrict__ W,
                  const float* __restrict__ bias, const u16t* __restrict__ wbf,
                  float* __restrict__ out) {
  __shared__ __align__(16) char lds[LDS_BYTES];
  const int tid = threadIdx.x;

  // XCD-aware bijective swizzle (kept from R14: neutral, harmless).
  const int flat = blockIdx.y * gridDim.x + blockIdx.x;   // 0..2047
  const int swz = (flat & 7) * 256 + (flat >> 3);
  const int b = swz >> 6;          // batch 0..31
  const int p0 = (swz & 63) * PP;  // position tile

  const int wv = tid >> 6;
  const int lane = tid & 63;
  const int q = lane >> 4, r = lane & 15;
  const int jtq = q >> 1, half = q & 1;
  const int row = 16 * wv + r;   // this lane's W row (output channel - 1)

  u16t* Xt = (u16t*)(lds + OFF_XT);
  float* csq = (float*)(lds + OFF_CSQ);
  float* ht = (float*)(lds + OFF_HT) + wv * 16 * HTP;  // wave-private transpose tile
  float* red = (float*)(lds + OFF_RED);

  // W fragments: 5 uint4 = 20 VGPR, register-resident.
  uint4 wfrag[NKS];
#pragma unroll
  for (int ks = 0; ks < NKS; ++ks)
    wfrag[ks] = *(const uint4*)(wbf + row * KT + ks * 32 + q * 8);
  const float w0v = (row < NW) ? W[row * CD] : 0.f;
  const float bv = (row < NW) ? bias[row] : 0.f;

  // ---- P1: stage x (channels 1..15) position-major, float4-vectorized
  for (int t = tid; t < XR; t += 256) Xt[t * RSTR + 15] = 0;  // dummy ch, NaN-safe
  for (int e4 = tid; e4 < CSP * (XR / 4); e4 += 256) {
    int cs = e4 / (XR / 4);
    int t4 = e4 - cs * (XR / 4);
    int t = 4 * t4;
    int g0 = p0 - PAD + t;
    const float* src = x + ((size_t)b * CIN + cs + 1) * L_ + g0;
    float v0, v1, v2, v3;
    if (g0 >= 0 && g0 + 3 < L_) {
      float4 v = *(const float4*)src;
      v0 = v.x; v1 = v.y; v2 = v.z; v3 = v.w;
    } else {
      v0 = (g0 >= 0 && g0 < L_) ? src[0] : 0.f;
      v1 = (g0 + 1 >= 0 && g0 + 1 < L_) ? src[1] : 0.f;
      v2 = (g0 + 2 >= 0 && g0 + 2 < L_) ? src[2] : 0.f;
      v3 = (g0 + 3 >= 0 && g0 + 3 < L_) ? src[3] : 0.f;
    }
    u16t* dst = Xt + t * RSTR + cs;
    dst[0] = f2bf(v0);
    dst[RSTR] = f2bf(v1);
    dst[2 * RSTR] = f2bf(v2);
    dst[3 * RSTR] = f2bf(v3);
  }
  __syncthreads();

  // ---- P2: per-window-column sum of squares
  for (int t = tid; t < XR; t += 256) {
    const uint4* rw4 = (const uint4*)(Xt + t * RSTR);
    uint4 a = rw4[0], c = rw4[1];
    unsigned wds[8] = {a.x, a.y, a.z, a.w, c.x, c.y, c.z, c.w};
    float s = 0.f;
#pragma unroll
    for (int i = 0; i < 8; ++i) {
      float lo = bf2f((u16t)(wds[i] & 0xffffu));
      float hi = bf2f((u16t)(wds[i] >> 16));
      s = fmaf(lo, lo, s);
      s = fmaf(hi, hi, s);
    }
    csq[t] = s;
  }
  __syncthreads();

  // ---- P3: 4 groups of 4 subtiles; wave-private LDS transpose; nt 256B-seg stores
  const int cl = lane >> 4;          // channel sub-index for the store pass
  const int pj = lane & 15;          // position quad within the 64-pos group
  for (int grp = 0; grp < 4; ++grp) {
    f32x4 hreg[4];
#pragma unroll
    for (int sl = 0; sl < 4; ++sl) {
      const int s = grp * 4 + sl;
      // A fragments: lane (q,r) holds patch[pos=s*16+r][k=32ks+8q .. +7]
      bf16x8 av[NKS];
#pragma unroll
      for (int ks = 0; ks < NKS; ++ks) {
        int xrow = s * 16 + r + 2 * ks + jtq;
        av[ks] = *(const bf16x8*)(lds + OFF_XT + xrow * (RSTR * 2) + half * 16);
      }
      f32x4 accA = {0.f, 0.f, 0.f, 0.f}, accB = {0.f, 0.f, 0.f, 0.f};
      {
        union { uint4 u; bf16x8 v; } w0, w1, w2, w3, w4;
        w0.u = wfrag[0]; w1.u = wfrag[1]; w2.u = wfrag[2];
        w3.u = wfrag[3]; w4.u = wfrag[4];
        accA = __builtin_amdgcn_mfma_f32_16x16x32_bf16(av[0], w0.v, accA, 0, 0, 0);
        accB = __builtin_amdgcn_mfma_f32_16x16x32_bf16(av[1], w1.v, accB, 0, 0, 0);
        accA = __builtin_amdgcn_mfma_f32_16x16x32_bf16(av[2], w2.v, accA, 0, 0, 0);
        accB = __builtin_amdgcn_mfma_f32_16x16x32_bf16(av[3], w3.v, accB, 0, 0, 0);
        accA = __builtin_amdgcn_mfma_f32_16x16x32_bf16(av[4], w4.v, accA, 0, 0, 0);
      }
      const f32x4 acc = accA + accB;

      // time channel from csq (running 9-window sums)
      const int base = s * 16 + q * 4;
      const f32x4* c4 = (const f32x4*)(csq + base);
      f32x4 ca = c4[0], cm = c4[1], cc = c4[2];
      float v[12] = {ca[0], ca[1], ca[2], ca[3], cm[0], cm[1], cm[2], cm[3],
                     cc[0], cc[1], cc[2], cc[3]};
      float ws0 = ((v[0] + v[1]) + (v[2] + v[3])) + ((v[4] + v[5]) + (v[6] + v[7])) + v[8];
      float ws1 = ws0 - v[0] + v[9];
      float ws2 = ws1 - v[1] + v[10];
      float ws3 = ws2 - v[2] + v[11];
      const float wsv[4] = {ws0, ws1, ws2, ws3};
      f32x4 hh;
#pragma unroll
      for (int g = 0; g < 4; ++g) {
        float tmg = sqrtf(1.f + wsv[g]);
        hh[g] = fmaxf(fmaf(w0v, tmg, acc[g]) + bv, 0.f);
      }
      hreg[sl] = hh;
    }

    // wave-private transpose: write [ch-local r][pos], read back [4j+cl][pj*4]
#pragma unroll
    for (int sl = 0; sl < 4; ++sl)
      *(f32x4*)(ht + r * HTP + sl * 16 + q * 4) = hreg[sl];

    f32x4 ps = {0.f, 0.f, 0.f, 0.f};
#pragma unroll
    for (int j = 0; j < 4; ++j) {
      const int rw = 4 * j + cl;               // tile-local channel row 0..15
      f32x4 hv = *(const f32x4*)(ht + rw * HTP + pj * 4);
      ps += hv * hv;
      const int oc = 16 * wv + rw;             // global W row
      if (oc < NW) {
        nt_store4(out + ((size_t)b * OUTC + oc + 1) * L_ + p0 + grp * 64 + pj * 4,
                  hv[0], hv[1], hv[2], hv[3]);
      }
    }
    // reduce ps over the 4 cl-groups -> 16-channel partial for this wave
#pragma unroll
    for (int g = 0; g < 4; ++g) {
      ps[g] += __shfl_xor(ps[g], 16, 64);
      ps[g] += __shfl_xor(ps[g], 32, 64);
    }
    if (lane < 16)
      *(f32x4*)(red + wv * PP + grp * 64 + lane * 4) = ps;
  }
  __syncthreads();

  // ---- P4: cross-wave combine -> t_out (channel 0), contiguous 1KB nt store
  if (wv == 0) {
    const f32x4* r4 = (const f32x4*)red;
    f32x4 s0 = r4[lane], s1 = r4[64 + lane], s2 = r4[128 + lane], s3 = r4[192 + lane];
    nt_store4(out + (size_t)b * OUTC * L_ + p0 + 4 * lane,
              sqrtf(1.f + s0[0] + s1[0] + s2[0] + s3[0]),
              sqrtf(1.f + s0[1] + s1[1] + s2[1] + s3[1]),
              sqrtf(1.f + s0[2] + s1[2] + s2[2] + s3[2]),
              sqrtf(1.f + s0[3] + s1[3] + s2[3] + s3[3]));
  }
}

extern "C" void kernel_launch(void* const* d_in, const int* in_sizes, int n_in,
                              void* d_out, int out_size, void* d_ws, size_t ws_size,
                              hipStream_t stream) {
  const float* x = (const float*)d_in[0];
  const float* W = (const float*)d_in[1];
  const float* bias = (const float*)d_in[2];
  float* out = (float*)d_out;
  u16t* wbf = (u16t*)d_ws;  // 64*160*2 = 20480 B

  hipLaunchKernelGGL(prep_w, dim3((OUTC * KT + 255) / 256), dim3(256), 0, stream, W, wbf);
  hipLaunchKernelGGL(lorentz_mfma, dim3(L_ / PP, B_), dim3(256), 0, stream,
                     x, W, bias, wbf, out);
}